// Round 8
// baseline (181.767 us; speedup 1.0000x reference)
//
#include <hip/hip_runtime.h>
#include <math.h>

#define NBATCH 4
#define CIN    256
#define CBOT   128
#define NPIX   4096
#define NPART  6          // i-split; flash grid 32*6*4 = 768 = 3 blocks/CU exact
#define LOG2E  1.44269504f

typedef __attribute__((ext_vector_type(4))) float f32x4;
typedef __attribute__((ext_vector_type(8))) short bf16x8;

__device__ __forceinline__ unsigned short f2bf(float f) {
    union { float f; unsigned u; } v; v.f = f;
    unsigned r = (v.u + 0x7FFFu + ((v.u >> 16) & 1u)) >> 16;   // RNE
    return (unsigned short)r;
}
// packed 2x bf16 (a low, b high). m240: NO clang builtin on gfx950 — force
// the single HW instruction (VOP3, RNE — bit-identical to the soft fallback).
__device__ __forceinline__ unsigned pk2bf(float a, float b) {
#if __has_builtin(__builtin_amdgcn_cvt_pk_bf16_f32)
    auto r = __builtin_amdgcn_cvt_pk_bf16_f32(a, b);
    unsigned u; __builtin_memcpy(&u, &r, 4); return u;
#else
    unsigned r;
    asm("v_cvt_pk_bf16_f32 %0, %1, %2" : "=v"(r) : "v"(a), "v"(b));
    return r;
#endif
}
__device__ __forceinline__ float fexp2(float x) {
#if __has_builtin(__builtin_amdgcn_exp2f)
    return __builtin_amdgcn_exp2f(x);
#else
    float r;
    asm("v_exp_f32 %0, %1" : "=v"(r) : "v"(x));
    return r;
#endif
}
// gfx950 row-swap primitives: swap32: a'=[a0,a1,b0,b1] b'=[a2,a3,b2,b3]
//                             swap16: a'=[a0,b0,a2,b2] b'=[a1,b1,a3,b3]  (16-lane rows)
__device__ __forceinline__ void plswap32(unsigned &a, unsigned &b) {
#if __has_builtin(__builtin_amdgcn_permlane32_swap)
    auto r = __builtin_amdgcn_permlane32_swap(a, b, false, false);
    a = (unsigned)r[0]; b = (unsigned)r[1];
#else
    asm volatile("v_permlane32_swap_b32 %0, %1" : "+v"(a), "+v"(b));
#endif
}
__device__ __forceinline__ void plswap16(unsigned &a, unsigned &b) {
#if __has_builtin(__builtin_amdgcn_permlane16_swap)
    auto r = __builtin_amdgcn_permlane16_swap(a, b, false, false);
    a = (unsigned)r[0]; b = (unsigned)r[1];
#else
    asm volatile("v_permlane16_swap_b32 %0, %1" : "+v"(a), "+v"(b));
#endif
}

// ---------------------------------------------------------------------------
// Kernel W: weights fp32 -> bf16 once. Layout Wq|Wk|Wv|Wo row-major, 32768 ea.
// Wk pre-scaled by log2(e). grid (128), 256 thr.
// ---------------------------------------------------------------------------
__global__ __launch_bounds__(256) void k_wcvt(
    const float* __restrict__ Wq, const float* __restrict__ Wk,
    const float* __restrict__ Wv, const float* __restrict__ Wo,
    unsigned short* __restrict__ Wb)
{
    const int f4 = (blockIdx.x * 256 + threadIdx.x) * 4;   // 131072 total elems
    const int reg = f4 >> 15, loc = f4 & 32767;
    const float* __restrict__ W = (reg == 0) ? Wq : (reg == 1) ? Wk : (reg == 2) ? Wv : Wo;
    const float sc = (reg == 1) ? LOG2E : 1.f;
    float4 v = *(const float4*)(W + loc);
    uint2 u;
    u.x = pk2bf(v.x * sc, v.y * sc);
    u.y = pk2bf(v.z * sc, v.w * sc);
    *(uint2*)&Wb[f4] = u;
}

// ---------------------------------------------------------------------------
// Kernel 1: fused X-transpose + Q/K/V projection. TLP build: p-tile 16,
// grid (256, 4) = 1024 blocks = 4/CU (was 512 = 2/CU, latency-bound).
// 256 thr = 4 waves (each: 32 o x 16 p).
// ---------------------------------------------------------------------------
__global__ __launch_bounds__(256) void k_qkvx(
    const float* __restrict__ X,
    const unsigned short* __restrict__ Wb,
    const float* __restrict__ bq, const float* __restrict__ bk,
    const float* __restrict__ bv,
    unsigned short* __restrict__ Qt, unsigned short* __restrict__ Kt,
    unsigned short* __restrict__ Vt)
{
    __shared__ __align__(16) unsigned short Xs[16][264];  // [p_local][c], pad 8
    const int tid = threadIdx.x;
    const int wv = tid >> 6, lane = tid & 63;
    const int grp = lane & 15, quad = lane >> 4;
    const int pbase = blockIdx.x * 16;
    const int b     = blockIdx.y;
    const float* __restrict__ Xg = X + (size_t)b * CIN * NPIX + pbase;

    // stage: f = c*4 + pg4; 16 pixels/row = 4 float4 per channel row
#pragma unroll
    for (int k = 0; k < 4; ++k) {
        int f = tid + 256 * k;
        int c = f >> 2, pg = (f & 3) << 2;
        float4 v = *(const float4*)(Xg + (size_t)c * NPIX + pg);
        unsigned uxy = pk2bf(v.x, v.y);
        unsigned uzw = pk2bf(v.z, v.w);
        Xs[pg + 0][c] = (unsigned short)uxy;
        Xs[pg + 1][c] = (unsigned short)(uxy >> 16);
        Xs[pg + 2][c] = (unsigned short)uzw;
        Xs[pg + 3][c] = (unsigned short)(uzw >> 16);
    }
    __syncthreads();

    const unsigned short* __restrict__ Wqb = Wb;
    const unsigned short* __restrict__ Wkb = Wb + 32768;
    const unsigned short* __restrict__ Wvb = Wb + 65536;
    const int obase = 32 * wv;

    f32x4 aQ[2], aK[2], aV[2];
#pragma unroll
    for (int mt = 0; mt < 2; ++mt) { aQ[mt] = (f32x4)0.f; aK[mt] = (f32x4)0.f; aV[mt] = (f32x4)0.f; }

    for (int ks = 0; ks < 8; ++ks) {
        bf16x8 bx = *(const bf16x8*)&Xs[grp][ks * 32 + quad * 8];
        bf16x8 wq_[2], wk_[2], wv_[2];
#pragma unroll
        for (int mt = 0; mt < 2; ++mt) {
            const size_t roff = (size_t)(obase + mt * 16 + grp) * CIN + ks * 32 + quad * 8;
            wq_[mt] = *(const bf16x8*)&Wqb[roff];
            wk_[mt] = *(const bf16x8*)&Wkb[roff];
            wv_[mt] = *(const bf16x8*)&Wvb[roff];
        }
#pragma unroll
        for (int mt = 0; mt < 2; ++mt) {
            aQ[mt] = __builtin_amdgcn_mfma_f32_16x16x32_bf16(wq_[mt], bx, aQ[mt], 0, 0, 0);
            aK[mt] = __builtin_amdgcn_mfma_f32_16x16x32_bf16(wk_[mt], bx, aK[mt], 0, 0, 0);
            // V natural layout: m = p (bx as A), n = o
            aV[mt] = __builtin_amdgcn_mfma_f32_16x16x32_bf16(bx, wv_[mt], aV[mt], 0, 0, 0);
        }
    }

    // Q, K stores: transposed [p][o], bias added (bk scaled by log2 e).
    unsigned short* Qb_ = Qt + (size_t)b * NPIX * CBOT;
    unsigned short* Kb_ = Kt + (size_t)b * NPIX * CBOT;
#pragma unroll
    for (int mt = 0; mt < 2; ++mt) {
        int o0 = obase + mt * 16 + quad * 4;
        float b4q[4], b4k[4];
#pragma unroll
        for (int r = 0; r < 4; ++r) { b4q[r] = bq[o0 + r]; b4k[r] = bk[o0 + r] * LOG2E; }
        int p = pbase + grp;
        uint2 uq, uk;
        uq.x = pk2bf(aQ[mt][0] + b4q[0], aQ[mt][1] + b4q[1]);
        uq.y = pk2bf(aQ[mt][2] + b4q[2], aQ[mt][3] + b4q[3]);
        uk.x = pk2bf(aK[mt][0] + b4k[0], aK[mt][1] + b4k[1]);
        uk.y = pk2bf(aK[mt][2] + b4k[2], aK[mt][3] + b4k[3]);
        *(uint2*)&Qb_[(size_t)p * CBOT + o0] = uq;
        *(uint2*)&Kb_[(size_t)p * CBOT + o0] = uk;
    }
    // V store: natural [o][p], bias added.  (m=p tile of 16, n=o 2 tiles)
    unsigned short* Vb_ = Vt + (size_t)b * CBOT * NPIX;
#pragma unroll
    for (int nt = 0; nt < 2; ++nt) {
        int o = obase + nt * 16 + grp;
        float bb = bv[o];
        int p0 = pbase + quad * 4;
        uint2 u;
        u.x = pk2bf(aV[nt][0] + bb, aV[nt][1] + bb);
        u.y = pk2bf(aV[nt][2] + bb, aV[nt][3] + bb);
        *(uint2*)&Vb_[(size_t)o * NPIX + p0] = u;
    }
}

// ---------------------------------------------------------------------------
// Kernel 2: flash attention — R7 structure + un-squeezed registers.
// (256,3) empirically caps alloc at ~85 regs, which forced late load issue
// (exposed global latency between barriers). Occupancy is GRID-bound at 3
// blocks/CU (12 waves x ~110 regs << 2048/SIMD pool), so (256,2) keeps 3
// resident while letting the compiler hold a persistent qreg/vreg prefetch
// issued a FULL ITERATION ahead (R1/R4-proven ~96-116 regs, no spill).
// Single-buffer Qs+Vs (35.8KB), 2 barriers/iter. XCD remap from R7.
// grid (32, NPART, NBATCH), 256 thr = 4 waves.
// ---------------------------------------------------------------------------
__global__ __launch_bounds__(256, 2) void k_flash(
    const unsigned short* __restrict__ Qt,
    const unsigned short* __restrict__ Kt,
    const unsigned short* __restrict__ Vt,
    unsigned short* __restrict__ Opart,
    float* __restrict__ Lpart)
{
    __shared__ __align__(16) unsigned short Qs[64][136];   // [i][c] pad 8
    __shared__ __align__(16) unsigned short Vs[128][72];   // [c][i] pad 8
    const int tid  = threadIdx.x;
    const int wv   = tid >> 6, lane = tid & 63;
    const int grp  = lane & 15, quad = lane >> 4;

    // XCD remap (bijective): dispatch id%8 == blockIdx.x%8 == g.
    const int x    = blockIdx.x;                 // 0..31
    const int y    = blockIdx.y;                 // 0..5
    const int z    = blockIdx.z;                 // 0..3
    const int g    = x & 7;
    const int u    = y * 16 + ((x >> 3) + 4 * z);  // 0..95
    const int pair = g * 3 + (u >> 5);             // 0..23
    const int jp   = u & 31;                       // 0..31
    const int b    = pair / 6;
    const int part = pair % 6;
    const int jblk = jp * 128;
    const int tbeg = (part * 32) / 3;              // 0,10,21,32,42,53
    const int tend = ((part + 1) * 32) / 3;
    const unsigned short* __restrict__ Qb = Qt + (size_t)b * NPIX * CBOT;
    const unsigned short* __restrict__ Kb = Kt + (size_t)b * NPIX * CBOT;
    const unsigned short* __restrict__ Vb = Vt + (size_t)b * CBOT * NPIX;

    // K tile (block-invariant) as B-frags [nt][ks]: col j = grp, k = c.
    bf16x8 bk[2][4];
#pragma unroll
    for (int nt = 0; nt < 2; ++nt)
#pragma unroll
        for (int ks = 0; ks < 4; ++ks)
            bk[nt][ks] = *(const bf16x8*)&Kb[
                (size_t)(jblk + wv * 32 + nt * 16 + grp) * CBOT + ks * 32 + quad * 8];

    bf16x8 aones;
#pragma unroll
    for (int t = 0; t < 8; ++t) aones[t] = (short)0x3F80;   // 1.0 bf16

    f32x4 o[8][2];          // [c-tile][j-tile]: row c, col j
#pragma unroll
    for (int ct = 0; ct < 8; ++ct) { o[ct][0] = (f32x4)0.f; o[ct][1] = (f32x4)0.f; }
    f32x4 lacc[2] = {(f32x4)0.f, (f32x4)0.f};

    const int qrow = tid >> 4, qch = tid & 15;
    const int vrow = tid >> 3, vch = tid & 7;
    bf16x8 qreg[4], vreg[4];
    // prologue: tile tbeg -> LDS; prefetch tile tbeg+1 into regs
#pragma unroll
    for (int k = 0; k < 4; ++k) {
        qreg[k] = *(const bf16x8*)&Qb[(size_t)(tbeg * 64 + qrow + 16 * k) * CBOT + qch * 8];
        vreg[k] = *(const bf16x8*)&Vb[(size_t)(vrow + 32 * k) * NPIX + tbeg * 64 + vch * 8];
    }
#pragma unroll
    for (int k = 0; k < 4; ++k) {
        *(bf16x8*)&Qs[qrow + 16 * k][qch * 8] = qreg[k];
        *(bf16x8*)&Vs[vrow + 32 * k][vch * 8] = vreg[k];
    }
    {
        const int i1 = (tbeg + 1) * 64;
#pragma unroll
        for (int k = 0; k < 4; ++k) {
            qreg[k] = *(const bf16x8*)&Qb[(size_t)(i1 + qrow + 16 * k) * CBOT + qch * 8];
            vreg[k] = *(const bf16x8*)&Vb[(size_t)(vrow + 32 * k) * NPIX + i1 + vch * 8];
        }
    }
    __syncthreads();

    for (int it = tbeg; it < tend; ++it) {
        // QK^T: sf[mt][nt] holds score[i = mt*16+quad*4+r][j = nt*16+grp]
        f32x4 sf[4][2];
#pragma unroll
        for (int mt = 0; mt < 4; ++mt) { sf[mt][0] = (f32x4)0.f; sf[mt][1] = (f32x4)0.f; }
        __builtin_amdgcn_s_setprio(1);
#pragma unroll
        for (int mt = 0; mt < 4; ++mt)
#pragma unroll
            for (int ks = 0; ks < 4; ++ks) {
                bf16x8 aq_ = *(const bf16x8*)&Qs[mt * 16 + grp][ks * 32 + quad * 8];
                sf[mt][0] = __builtin_amdgcn_mfma_f32_16x16x32_bf16(aq_, bk[0][ks], sf[mt][0], 0, 0, 0);
                sf[mt][1] = __builtin_amdgcn_mfma_f32_16x16x32_bf16(aq_, bk[1][ks], sf[mt][1], 0, 0, 0);
            }
        __builtin_amdgcn_s_setprio(0);

        // p = 2^s (Kt pre-scaled); pack + permlane-transpose into PV B-frags.
        bf16x8 pf[2][2];    // [nt][h]
#pragma unroll
        for (int nt = 0; nt < 2; ++nt)
#pragma unroll
            for (int h = 0; h < 2; ++h) {
                unsigned u0a = pk2bf(fexp2(sf[2 * h][nt][0]),     fexp2(sf[2 * h][nt][1]));
                unsigned u1a = pk2bf(fexp2(sf[2 * h][nt][2]),     fexp2(sf[2 * h][nt][3]));
                unsigned u0b = pk2bf(fexp2(sf[2 * h + 1][nt][0]), fexp2(sf[2 * h + 1][nt][1]));
                unsigned u1b = pk2bf(fexp2(sf[2 * h + 1][nt][2]), fexp2(sf[2 * h + 1][nt][3]));
                plswap32(u0a, u0b); plswap16(u0a, u0b);
                plswap32(u1a, u1b); plswap16(u1a, u1b);
                union { unsigned uu[4]; bf16x8 v; } cvt;
                cvt.uu[0] = u0a; cvt.uu[1] = u1a; cvt.uu[2] = u0b; cvt.uu[3] = u1b;
                pf[nt][h] = cvt.v;
            }

        // PV: o[ct][nt] += V (A, rows c, from LDS) x P (B, cols j)
        __builtin_amdgcn_s_setprio(1);
#pragma unroll
        for (int ct = 0; ct < 8; ++ct)
#pragma unroll
            for (int h = 0; h < 2; ++h) {
                bf16x8 av_ = *(const bf16x8*)&Vs[ct * 16 + grp][h * 32 + quad * 8];
                o[ct][0] = __builtin_amdgcn_mfma_f32_16x16x32_bf16(av_, pf[0][h], o[ct][0], 0, 0, 0);
                o[ct][1] = __builtin_amdgcn_mfma_f32_16x16x32_bf16(av_, pf[1][h], o[ct][1], 0, 0, 0);
            }
        // l[j] = sum_i P[i][j] via ones-A MFMA (all output rows identical)
#pragma unroll
        for (int nt = 0; nt < 2; ++nt) {
            lacc[nt] = __builtin_amdgcn_mfma_f32_16x16x32_bf16(aones, pf[nt][0], lacc[nt], 0, 0, 0);
            lacc[nt] = __builtin_amdgcn_mfma_f32_16x16x32_bf16(aones, pf[nt][1], lacc[nt], 0, 0, 0);
        }
        __builtin_amdgcn_s_setprio(0);

        if (it + 1 < tend) {
            __syncthreads();                    // all waves done reading Qs/Vs
#pragma unroll
            for (int k = 0; k < 4; ++k) {
                *(bf16x8*)&Qs[qrow + 16 * k][qch * 8] = qreg[k];
                *(bf16x8*)&Vs[vrow + 32 * k][vch * 8] = vreg[k];
            }
            if (it + 2 < tend) {
                const int i2 = (it + 2) * 64;
#pragma unroll
                for (int k = 0; k < 4; ++k) {
                    qreg[k] = *(const bf16x8*)&Qb[(size_t)(i2 + qrow + 16 * k) * CBOT + qch * 8];
                    vreg[k] = *(const bf16x8*)&Vb[(size_t)(vrow + 32 * k) * NPIX + i2 + vch * 8];
                }
            }
            __syncthreads();                    // writes visible before next QK
        }
    }

    // epilogue: o rows c = ct*16+quad*4+r (4 consecutive c per lane -> uint2)
    const int pbI = part * NBATCH + b;
    unsigned short* Ob = Opart + ((size_t)pbI * NPIX + jblk) * CBOT;
#pragma unroll
    for (int nt = 0; nt < 2; ++nt) {
        const size_t jrow = (size_t)(wv * 32 + nt * 16 + grp) * CBOT;
#pragma unroll
        for (int ct = 0; ct < 8; ++ct) {
            uint2 uo;
            uo.x = pk2bf(o[ct][nt][0], o[ct][nt][1]);
            uo.y = pk2bf(o[ct][nt][2], o[ct][nt][3]);
            *(uint2*)&Ob[jrow + ct * 16 + quad * 4] = uo;
        }
    }
    if (quad == 0) {
#pragma unroll
        for (int nt = 0; nt < 2; ++nt)
            Lpart[(size_t)pbI * NPIX + jblk + wv * 32 + nt * 16 + grp] =
                lacc[nt][0];
    }
}

// ---------------------------------------------------------------------------
// Kernel 3: out-proj + residual; partials combined IN the MFMA accumulator.
// TLP build: p-tile 16, grid (256, 4) = 1024 blocks = 4/CU (was 512 = 2/CU).
// 256 thr = 4 waves (n=64 o each).
// ---------------------------------------------------------------------------
__global__ __launch_bounds__(256) void k_oproj(
    const unsigned short* __restrict__ Opart, const float* __restrict__ Lpart,
    const unsigned short* __restrict__ Wob, const float* __restrict__ bo,
    const float* __restrict__ gamma, const float* __restrict__ X,
    float* __restrict__ Out)
{
    const int tid = threadIdx.x;
    const int wv = tid >> 6, lane = tid & 63;
    const int grp = lane & 15, quad = lane >> 4;
    const int pbase = blockIdx.x * 16;
    const int b     = blockIdx.y;
    const int obase = 64 * wv;

    f32x4 acc[4];
#pragma unroll
    for (int nt = 0; nt < 4; ++nt) acc[nt] = (f32x4)0.f;

    for (int ks = 0; ks < 4; ++ks) {
        bf16x8 bw[4];
#pragma unroll
        for (int nt = 0; nt < 4; ++nt)
            bw[nt] = *(const bf16x8*)&Wob[(size_t)(obase + nt * 16 + grp) * CBOT + ks * 32 + quad * 8];
        const int p = pbase + grp;
#pragma unroll
        for (int part = 0; part < NPART; ++part) {
            bf16x8 ao = *(const bf16x8*)&Opart[
                ((size_t)(part * NBATCH + b) * NPIX + p) * CBOT + ks * 32 + quad * 8];
#pragma unroll
            for (int nt = 0; nt < 4; ++nt)
                acc[nt] = __builtin_amdgcn_mfma_f32_16x16x32_bf16(ao, bw[nt], acc[nt], 0, 0, 0);
        }
    }

    float linv[4];
#pragma unroll
    for (int r = 0; r < 4; ++r) {
        int p = pbase + quad * 4 + r;
        float ls = 0.f;
#pragma unroll
        for (int part = 0; part < NPART; ++part)
            ls += Lpart[(size_t)(part * NBATCH + b) * NPIX + p];
        linv[r] = 1.f / ls;
    }
    float gm = gamma[0];
#pragma unroll
    for (int nt = 0; nt < 4; ++nt) {
        int o = obase + nt * 16 + grp;
        float bb = bo[o];
        int p0 = pbase + quad * 4;
        size_t base = (size_t)b * CIN * NPIX + (size_t)o * NPIX + p0;
        float4 x4 = *(const float4*)(X + base);
        float4 r4;
        r4.x = gm * (acc[nt][0] * linv[0] + bb) + x4.x;
        r4.y = gm * (acc[nt][1] * linv[1] + bb) + x4.y;
        r4.z = gm * (acc[nt][2] * linv[2] + bb) + x4.z;
        r4.w = gm * (acc[nt][3] * linv[3] + bb) + x4.w;
        *(float4*)(Out + base) = r4;
    }
}

extern "C" void kernel_launch(void* const* d_in, const int* in_sizes, int n_in,
                              void* d_out, int out_size, void* d_ws, size_t ws_size,
                              hipStream_t stream)
{
    (void)in_sizes; (void)n_in; (void)out_size; (void)ws_size;
    const float* X     = (const float*)d_in[0];
    const float* Wq    = (const float*)d_in[1];
    const float* bq    = (const float*)d_in[2];
    const float* Wk    = (const float*)d_in[3];
    const float* bk    = (const float*)d_in[4];
    const float* Wv    = (const float*)d_in[5];
    const float* bv    = (const float*)d_in[6];
    const float* Wo    = (const float*)d_in[7];
    const float* bo    = (const float*)d_in[8];
    const float* gamma = (const float*)d_in[9];
    float* out = (float*)d_out;

    // ws: Qt|Kt|Vt bf16 4MB ea | Opart bf16 x6 24MB | Lpart 384KB | Wb 256KB
    const size_t BNC = (size_t)NBATCH * NPIX * CBOT;   // 2M elems
    unsigned short* Qt    = (unsigned short*)d_ws;
    unsigned short* Kt    = Qt + BNC;
    unsigned short* Vt    = Kt + BNC;
    unsigned short* Opart = Vt + BNC;
    float*          Lpart = (float*)(Opart + (size_t)NPART * BNC);
    unsigned short* Wb    = (unsigned short*)(Lpart + (size_t)NPART * NBATCH * NPIX);

    k_wcvt <<<dim3(128),               256, 0, stream>>>(Wq, Wk, Wv, Wo, Wb);
    k_qkvx <<<dim3(256, NBATCH),       256, 0, stream>>>(X, Wb, bq, bk, bv, Qt, Kt, Vt);
    k_flash<<<dim3(32, NPART, NBATCH), 256, 0, stream>>>(Qt, Kt, Vt, Opart, Lpart);
    k_oproj<<<dim3(256, NBATCH),       256, 0, stream>>>(Opart, Lpart, Wb + 98304, bo, gamma, X, out);
}

// Round 9
// 156.605 us; speedup vs baseline: 1.1607x; 1.1607x over previous
//
#include <hip/hip_runtime.h>
#include <math.h>

#define NBATCH 4
#define CIN    256
#define CBOT   128
#define NPIX   4096
#define NPART  4          // i-split; flash grid 32*4*4 = 512 = 2 blocks/CU exact
#define LOG2E  1.44269504f

typedef __attribute__((ext_vector_type(4))) float f32x4;
typedef __attribute__((ext_vector_type(8))) short bf16x8;

__device__ __forceinline__ unsigned short f2bf(float f) {
    union { float f; unsigned u; } v; v.f = f;
    unsigned r = (v.u + 0x7FFFu + ((v.u >> 16) & 1u)) >> 16;   // RNE
    return (unsigned short)r;
}
// packed 2x bf16 (a low, b high). m240: NO clang builtin on gfx950 — force
// the single HW instruction (VOP3, RNE — bit-identical to the soft fallback).
__device__ __forceinline__ unsigned pk2bf(float a, float b) {
#if __has_builtin(__builtin_amdgcn_cvt_pk_bf16_f32)
    auto r = __builtin_amdgcn_cvt_pk_bf16_f32(a, b);
    unsigned u; __builtin_memcpy(&u, &r, 4); return u;
#else
    unsigned r;
    asm("v_cvt_pk_bf16_f32 %0, %1, %2" : "=v"(r) : "v"(a), "v"(b));
    return r;
#endif
}
__device__ __forceinline__ float fexp2(float x) {
#if __has_builtin(__builtin_amdgcn_exp2f)
    return __builtin_amdgcn_exp2f(x);
#else
    float r;
    asm("v_exp_f32 %0, %1" : "=v"(r) : "v"(x));
    return r;
#endif
}
// gfx950 row-swap primitives: swap32: a'=[a0,a1,b0,b1] b'=[a2,a3,b2,b3]
//                             swap16: a'=[a0,b0,a2,b2] b'=[a1,b1,a3,b3]  (16-lane rows)
__device__ __forceinline__ void plswap32(unsigned &a, unsigned &b) {
#if __has_builtin(__builtin_amdgcn_permlane32_swap)
    auto r = __builtin_amdgcn_permlane32_swap(a, b, false, false);
    a = (unsigned)r[0]; b = (unsigned)r[1];
#else
    asm volatile("v_permlane32_swap_b32 %0, %1" : "+v"(a), "+v"(b));
#endif
}
__device__ __forceinline__ void plswap16(unsigned &a, unsigned &b) {
#if __has_builtin(__builtin_amdgcn_permlane16_swap)
    auto r = __builtin_amdgcn_permlane16_swap(a, b, false, false);
    a = (unsigned)r[0]; b = (unsigned)r[1];
#else
    asm volatile("v_permlane16_swap_b32 %0, %1" : "+v"(a), "+v"(b));
#endif
}

// ---------------------------------------------------------------------------
// Kernel W: weights fp32 -> bf16 once. Layout Wq|Wk|Wv|Wo row-major, 32768 ea.
// Wk pre-scaled by log2(e). grid (128), 256 thr.
// ---------------------------------------------------------------------------
__global__ __launch_bounds__(256) void k_wcvt(
    const float* __restrict__ Wq, const float* __restrict__ Wk,
    const float* __restrict__ Wv, const float* __restrict__ Wo,
    unsigned short* __restrict__ Wb)
{
    const int f4 = (blockIdx.x * 256 + threadIdx.x) * 4;   // 131072 total elems
    const int reg = f4 >> 15, loc = f4 & 32767;
    const float* __restrict__ W = (reg == 0) ? Wq : (reg == 1) ? Wk : (reg == 2) ? Wv : Wo;
    const float sc = (reg == 1) ? LOG2E : 1.f;
    float4 v = *(const float4*)(W + loc);
    uint2 u;
    u.x = pk2bf(v.x * sc, v.y * sc);
    u.y = pk2bf(v.z * sc, v.w * sc);
    *(uint2*)&Wb[f4] = u;
}

// ---------------------------------------------------------------------------
// Kernel 1: fused X-transpose + Q/K/V projection (p-32 tile — p-16 regressed
// +14us in R8: weight reloads per block dominate, amortize over 32 pixels).
// grid (128 p-tiles of 32, 4 b), 256 thr = 4 waves (each: 32 o x 32 p).
// ---------------------------------------------------------------------------
__global__ __launch_bounds__(256) void k_qkvx(
    const float* __restrict__ X,
    const unsigned short* __restrict__ Wb,
    const float* __restrict__ bq, const float* __restrict__ bk,
    const float* __restrict__ bv,
    unsigned short* __restrict__ Qt, unsigned short* __restrict__ Kt,
    unsigned short* __restrict__ Vt)
{
    __shared__ __align__(16) unsigned short Xs[32][264];  // [p_local][c], pad 8
    const int tid = threadIdx.x;
    const int wv = tid >> 6, lane = tid & 63;
    const int grp = lane & 15, quad = lane >> 4;
    const int pbase = blockIdx.x * 32;
    const int b     = blockIdx.y;
    const float* __restrict__ Xg = X + (size_t)b * CIN * NPIX + pbase;

    // stage: f = c*8 + pg; load float4 (4 consecutive pixels), pair-convert
    // with cvt_pk then scatter lo/hi halves (ds_write_b16 / _d16_hi).
#pragma unroll
    for (int k = 0; k < 8; ++k) {
        int f = tid + 256 * k;
        int c = f >> 3, pg = (f & 7) << 2;
        float4 v = *(const float4*)(Xg + (size_t)c * NPIX + pg);
        unsigned uxy = pk2bf(v.x, v.y);
        unsigned uzw = pk2bf(v.z, v.w);
        Xs[pg + 0][c] = (unsigned short)uxy;
        Xs[pg + 1][c] = (unsigned short)(uxy >> 16);
        Xs[pg + 2][c] = (unsigned short)uzw;
        Xs[pg + 3][c] = (unsigned short)(uzw >> 16);
    }
    __syncthreads();

    const unsigned short* __restrict__ Wqb = Wb;
    const unsigned short* __restrict__ Wkb = Wb + 32768;
    const unsigned short* __restrict__ Wvb = Wb + 65536;
    const int obase = 32 * wv;

    f32x4 aQ[2][2], aK[2][2], aV[2][2];
#pragma unroll
    for (int mt = 0; mt < 2; ++mt)
#pragma unroll
        for (int nt = 0; nt < 2; ++nt) {
            aQ[mt][nt] = (f32x4)0.f; aK[mt][nt] = (f32x4)0.f; aV[mt][nt] = (f32x4)0.f;
        }

    for (int ks = 0; ks < 8; ++ks) {
        bf16x8 bx[2];
#pragma unroll
        for (int nt = 0; nt < 2; ++nt)
            bx[nt] = *(const bf16x8*)&Xs[nt * 16 + grp][ks * 32 + quad * 8];
        bf16x8 wq_[2], wk_[2], wv_[2];
#pragma unroll
        for (int mt = 0; mt < 2; ++mt) {
            const size_t roff = (size_t)(obase + mt * 16 + grp) * CIN + ks * 32 + quad * 8;
            wq_[mt] = *(const bf16x8*)&Wqb[roff];
            wk_[mt] = *(const bf16x8*)&Wkb[roff];
            wv_[mt] = *(const bf16x8*)&Wvb[roff];
        }
#pragma unroll
        for (int mt = 0; mt < 2; ++mt)
#pragma unroll
            for (int nt = 0; nt < 2; ++nt) {
                aQ[mt][nt] = __builtin_amdgcn_mfma_f32_16x16x32_bf16(wq_[mt], bx[nt], aQ[mt][nt], 0, 0, 0);
                aK[mt][nt] = __builtin_amdgcn_mfma_f32_16x16x32_bf16(wk_[mt], bx[nt], aK[mt][nt], 0, 0, 0);
                aV[mt][nt] = __builtin_amdgcn_mfma_f32_16x16x32_bf16(bx[mt], wv_[nt], aV[mt][nt], 0, 0, 0);
            }
    }

    // Q, K stores: transposed [p][o], bias added (bk scaled by log2 e).
    unsigned short* Qb_ = Qt + (size_t)b * NPIX * CBOT;
    unsigned short* Kb_ = Kt + (size_t)b * NPIX * CBOT;
#pragma unroll
    for (int mt = 0; mt < 2; ++mt) {
        int o0 = obase + mt * 16 + quad * 4;
        float b4q[4], b4k[4];
#pragma unroll
        for (int r = 0; r < 4; ++r) { b4q[r] = bq[o0 + r]; b4k[r] = bk[o0 + r] * LOG2E; }
#pragma unroll
        for (int nt = 0; nt < 2; ++nt) {
            int p = pbase + nt * 16 + grp;
            uint2 uq, uk;
            uq.x = pk2bf(aQ[mt][nt][0] + b4q[0], aQ[mt][nt][1] + b4q[1]);
            uq.y = pk2bf(aQ[mt][nt][2] + b4q[2], aQ[mt][nt][3] + b4q[3]);
            uk.x = pk2bf(aK[mt][nt][0] + b4k[0], aK[mt][nt][1] + b4k[1]);
            uk.y = pk2bf(aK[mt][nt][2] + b4k[2], aK[mt][nt][3] + b4k[3]);
            *(uint2*)&Qb_[(size_t)p * CBOT + o0] = uq;
            *(uint2*)&Kb_[(size_t)p * CBOT + o0] = uk;
        }
    }
    // V store: natural [o][p], bias added.  (m=p, n=o)
    unsigned short* Vb_ = Vt + (size_t)b * CBOT * NPIX;
#pragma unroll
    for (int nt = 0; nt < 2; ++nt) {
        int o = obase + nt * 16 + grp;
        float bb = bv[o];
#pragma unroll
        for (int mt = 0; mt < 2; ++mt) {
            int p0 = pbase + mt * 16 + quad * 4;
            uint2 u;
            u.x = pk2bf(aV[mt][nt][0] + bb, aV[mt][nt][1] + bb);
            u.y = pk2bf(aV[mt][nt][2] + bb, aV[mt][nt][3] + bb);
            *(uint2*)&Vb_[(size_t)o * NPIX + p0] = u;
        }
    }
}

// ---------------------------------------------------------------------------
// Kernel 2: flash attention — R7 structure (proven best: 43.3us) at NPART=4.
// Single-buffer Qs+Vs (35.8KB), 2 barriers/iter, LATE temp loads (issued
// after PV, before barrier 1 — latency hides under other waves' PV tails +
// barrier wait; temps born after sf/pf die). launch_bounds(256,3) as a reg-
// allocation cap (R7: 80 VGPR, zero spill). NPART=4 -> grid 512 = 2
// blocks/CU; Opart traffic 16MB (vs 24 at NPART=6; others -3us). XCD remap
// (R4-proven bijective, 16 pairs): one XCD owns 2 (part,b) pairs -> K 2MB +
// Q/V slices ~2MB <= 4MB L2.
// grid (32, NPART, NBATCH), 256 thr = 4 waves.
// ---------------------------------------------------------------------------
__global__ __launch_bounds__(256, 3) void k_flash(
    const unsigned short* __restrict__ Qt,
    const unsigned short* __restrict__ Kt,
    const unsigned short* __restrict__ Vt,
    unsigned short* __restrict__ Opart,
    float* __restrict__ Lpart)
{
    __shared__ __align__(16) unsigned short Qs[64][136];   // [i][c] pad 8
    __shared__ __align__(16) unsigned short Vs[128][72];   // [c][i] pad 8
    const int tid  = threadIdx.x;
    const int wv   = tid >> 6, lane = tid & 63;
    const int grp  = lane & 15, quad = lane >> 4;

    // XCD-locality remap (bijective; R4-proven): dispatch id%8 == x%8.
    const int x     = blockIdx.x;                        // 0..31
    const int pbRaw = blockIdx.y * NBATCH + blockIdx.z;  // 0..15
    const int jp    = (x >> 3) + 4 * (pbRaw >> 1);       // 0..31
    const int pbN   = (x & 7) * 2 + (pbRaw & 1);         // 0..15
    const int part  = pbN >> 2;                          // 0..3
    const int b     = pbN & 3;
    const int jblk  = jp * 128;
    const int tbeg  = part * 16;
    const int tend  = tbeg + 16;
    const unsigned short* __restrict__ Qb = Qt + (size_t)b * NPIX * CBOT;
    const unsigned short* __restrict__ Kb = Kt + (size_t)b * NPIX * CBOT;
    const unsigned short* __restrict__ Vb = Vt + (size_t)b * CBOT * NPIX;

    // K tile (block-invariant) as B-frags [nt][ks]: col j = grp, k = c.
    bf16x8 bk[2][4];
#pragma unroll
    for (int nt = 0; nt < 2; ++nt)
#pragma unroll
        for (int ks = 0; ks < 4; ++ks)
            bk[nt][ks] = *(const bf16x8*)&Kb[
                (size_t)(jblk + wv * 32 + nt * 16 + grp) * CBOT + ks * 32 + quad * 8];

    bf16x8 aones;
#pragma unroll
    for (int t = 0; t < 8; ++t) aones[t] = (short)0x3F80;   // 1.0 bf16

    f32x4 o[8][2];          // [c-tile][j-tile]: row c, col j
#pragma unroll
    for (int ct = 0; ct < 8; ++ct) { o[ct][0] = (f32x4)0.f; o[ct][1] = (f32x4)0.f; }
    f32x4 lacc[2] = {(f32x4)0.f, (f32x4)0.f};

    const int qrow = tid >> 4, qch = tid & 15;
    const int vrow = tid >> 3, vch = tid & 7;

    // prologue: stage tile tbeg (short-lived temps; no persistent prefetch)
    {
        bf16x8 tq[4], tv[4];
#pragma unroll
        for (int k = 0; k < 4; ++k) {
            tq[k] = *(const bf16x8*)&Qb[(size_t)(tbeg * 64 + qrow + 16 * k) * CBOT + qch * 8];
            tv[k] = *(const bf16x8*)&Vb[(size_t)(vrow + 32 * k) * NPIX + tbeg * 64 + vch * 8];
        }
#pragma unroll
        for (int k = 0; k < 4; ++k) {
            *(bf16x8*)&Qs[qrow + 16 * k][qch * 8] = tq[k];
            *(bf16x8*)&Vs[vrow + 32 * k][vch * 8] = tv[k];
        }
    }
    __syncthreads();

    for (int it = tbeg; it < tend; ++it) {
        // QK^T: sf[mt][nt] holds score[i = mt*16+quad*4+r][j = nt*16+grp]
        f32x4 sf[4][2];
#pragma unroll
        for (int mt = 0; mt < 4; ++mt) { sf[mt][0] = (f32x4)0.f; sf[mt][1] = (f32x4)0.f; }
        __builtin_amdgcn_s_setprio(1);
#pragma unroll
        for (int mt = 0; mt < 4; ++mt)
#pragma unroll
            for (int ks = 0; ks < 4; ++ks) {
                bf16x8 aq_ = *(const bf16x8*)&Qs[mt * 16 + grp][ks * 32 + quad * 8];
                sf[mt][0] = __builtin_amdgcn_mfma_f32_16x16x32_bf16(aq_, bk[0][ks], sf[mt][0], 0, 0, 0);
                sf[mt][1] = __builtin_amdgcn_mfma_f32_16x16x32_bf16(aq_, bk[1][ks], sf[mt][1], 0, 0, 0);
            }
        __builtin_amdgcn_s_setprio(0);

        // p = 2^s (Kt pre-scaled); pack + permlane-transpose into PV B-frags.
        bf16x8 pf[2][2];    // [nt][h]
#pragma unroll
        for (int nt = 0; nt < 2; ++nt)
#pragma unroll
            for (int h = 0; h < 2; ++h) {
                unsigned u0a = pk2bf(fexp2(sf[2 * h][nt][0]),     fexp2(sf[2 * h][nt][1]));
                unsigned u1a = pk2bf(fexp2(sf[2 * h][nt][2]),     fexp2(sf[2 * h][nt][3]));
                unsigned u0b = pk2bf(fexp2(sf[2 * h + 1][nt][0]), fexp2(sf[2 * h + 1][nt][1]));
                unsigned u1b = pk2bf(fexp2(sf[2 * h + 1][nt][2]), fexp2(sf[2 * h + 1][nt][3]));
                plswap32(u0a, u0b); plswap16(u0a, u0b);
                plswap32(u1a, u1b); plswap16(u1a, u1b);
                union { unsigned uu[4]; bf16x8 v; } cvt;
                cvt.uu[0] = u0a; cvt.uu[1] = u1a; cvt.uu[2] = u0b; cvt.uu[3] = u1b;
                pf[nt][h] = cvt.v;
            }

        // PV: o[ct][nt] += V (A, rows c, from LDS) x P (B, cols j)
        __builtin_amdgcn_s_setprio(1);
#pragma unroll
        for (int ct = 0; ct < 8; ++ct)
#pragma unroll
            for (int h = 0; h < 2; ++h) {
                bf16x8 av_ = *(const bf16x8*)&Vs[ct * 16 + grp][h * 32 + quad * 8];
                o[ct][0] = __builtin_amdgcn_mfma_f32_16x16x32_bf16(av_, pf[0][h], o[ct][0], 0, 0, 0);
                o[ct][1] = __builtin_amdgcn_mfma_f32_16x16x32_bf16(av_, pf[1][h], o[ct][1], 0, 0, 0);
            }
        // l[j] = sum_i P[i][j] via ones-A MFMA (all output rows identical)
#pragma unroll
        for (int nt = 0; nt < 2; ++nt) {
            lacc[nt] = __builtin_amdgcn_mfma_f32_16x16x32_bf16(aones, pf[nt][0], lacc[nt], 0, 0, 0);
            lacc[nt] = __builtin_amdgcn_mfma_f32_16x16x32_bf16(aones, pf[nt][1], lacc[nt], 0, 0, 0);
        }
        __builtin_amdgcn_s_setprio(0);

        if (it + 1 < tend) {
            // issue next-tile loads BEFORE barrier 1: latency overlaps the
            // other waves' PV tails + the barrier wait. Temps are born after
            // sf/pf die, so peak register pressure is unchanged.
            bf16x8 tq[4], tv[4];
            const size_t i1 = (size_t)(it + 1) * 64;
#pragma unroll
            for (int k = 0; k < 4; ++k) {
                tq[k] = *(const bf16x8*)&Qb[(i1 + qrow + 16 * k) * CBOT + qch * 8];
                tv[k] = *(const bf16x8*)&Vb[(size_t)(vrow + 32 * k) * NPIX + i1 + vch * 8];
            }
            __syncthreads();                    // all waves done reading Qs/Vs
#pragma unroll
            for (int k = 0; k < 4; ++k) {
                *(bf16x8*)&Qs[qrow + 16 * k][qch * 8] = tq[k];
                *(bf16x8*)&Vs[vrow + 32 * k][vch * 8] = tv[k];
            }
            __syncthreads();                    // writes visible before next QK
        }
    }

    // epilogue: o rows c = ct*16+quad*4+r (4 consecutive c per lane -> uint2)
    const int pbI = part * NBATCH + b;
    unsigned short* Ob = Opart + ((size_t)pbI * NPIX + jblk) * CBOT;
#pragma unroll
    for (int nt = 0; nt < 2; ++nt) {
        const size_t jrow = (size_t)(wv * 32 + nt * 16 + grp) * CBOT;
#pragma unroll
        for (int ct = 0; ct < 8; ++ct) {
            uint2 uo;
            uo.x = pk2bf(o[ct][nt][0], o[ct][nt][1]);
            uo.y = pk2bf(o[ct][nt][2], o[ct][nt][3]);
            *(uint2*)&Ob[jrow + ct * 16 + quad * 4] = uo;
        }
    }
    if (quad == 0) {
#pragma unroll
        for (int nt = 0; nt < 2; ++nt)
            Lpart[(size_t)pbI * NPIX + jblk + wv * 32 + nt * 16 + grp] =
                lacc[nt][0];
    }
}

// ---------------------------------------------------------------------------
// Kernel 3: out-proj + residual; partials combined IN the MFMA accumulator.
// p-32 tile (p-16 regressed in R8). grid (128, 4 b), 256 thr = 4 waves.
// ---------------------------------------------------------------------------
__global__ __launch_bounds__(256) void k_oproj(
    const unsigned short* __restrict__ Opart, const float* __restrict__ Lpart,
    const unsigned short* __restrict__ Wob, const float* __restrict__ bo,
    const float* __restrict__ gamma, const float* __restrict__ X,
    float* __restrict__ Out)
{
    const int tid = threadIdx.x;
    const int wv = tid >> 6, lane = tid & 63;
    const int grp = lane & 15, quad = lane >> 4;
    const int pbase = blockIdx.x * 32;
    const int b     = blockIdx.y;
    const int obase = 64 * wv;

    f32x4 acc[2][4];
#pragma unroll
    for (int mt = 0; mt < 2; ++mt)
#pragma unroll
        for (int nt = 0; nt < 4; ++nt) acc[mt][nt] = (f32x4)0.f;

    for (int ks = 0; ks < 4; ++ks) {
        bf16x8 bw[4];
#pragma unroll
        for (int nt = 0; nt < 4; ++nt)
            bw[nt] = *(const bf16x8*)&Wob[(size_t)(obase + nt * 16 + grp) * CBOT + ks * 32 + quad * 8];
#pragma unroll
        for (int mt = 0; mt < 2; ++mt) {
            int p = pbase + mt * 16 + grp;
#pragma unroll
            for (int part = 0; part < NPART; ++part) {
                bf16x8 ao = *(const bf16x8*)&Opart[
                    ((size_t)(part * NBATCH + b) * NPIX + p) * CBOT + ks * 32 + quad * 8];
#pragma unroll
                for (int nt = 0; nt < 4; ++nt)
                    acc[mt][nt] = __builtin_amdgcn_mfma_f32_16x16x32_bf16(ao, bw[nt], acc[mt][nt], 0, 0, 0);
            }
        }
    }

    float linv[2][4];
#pragma unroll
    for (int mt = 0; mt < 2; ++mt)
#pragma unroll
        for (int r = 0; r < 4; ++r) {
            int p = pbase + mt * 16 + quad * 4 + r;
            float ls = 0.f;
#pragma unroll
            for (int part = 0; part < NPART; ++part)
                ls += Lpart[(size_t)(part * NBATCH + b) * NPIX + p];
            linv[mt][r] = 1.f / ls;
        }
    float gm = gamma[0];
#pragma unroll
    for (int nt = 0; nt < 4; ++nt) {
        int o = obase + nt * 16 + grp;
        float bb = bo[o];
#pragma unroll
        for (int mt = 0; mt < 2; ++mt) {
            int p0 = pbase + mt * 16 + quad * 4;
            size_t base = (size_t)b * CIN * NPIX + (size_t)o * NPIX + p0;
            float4 x4 = *(const float4*)(X + base);
            float4 r4;
            r4.x = gm * (acc[mt][nt][0] * linv[mt][0] + bb) + x4.x;
            r4.y = gm * (acc[mt][nt][1] * linv[mt][1] + bb) + x4.y;
            r4.z = gm * (acc[mt][nt][2] * linv[mt][2] + bb) + x4.z;
            r4.w = gm * (acc[mt][nt][3] * linv[mt][3] + bb) + x4.w;
            *(float4*)(Out + base) = r4;
        }
    }
}

extern "C" void kernel_launch(void* const* d_in, const int* in_sizes, int n_in,
                              void* d_out, int out_size, void* d_ws, size_t ws_size,
                              hipStream_t stream)
{
    (void)in_sizes; (void)n_in; (void)out_size; (void)ws_size;
    const float* X     = (const float*)d_in[0];
    const float* Wq    = (const float*)d_in[1];
    const float* bq    = (const float*)d_in[2];
    const float* Wk    = (const float*)d_in[3];
    const float* bk    = (const float*)d_in[4];
    const float* Wv    = (const float*)d_in[5];
    const float* bv    = (const float*)d_in[6];
    const float* Wo    = (const float*)d_in[7];
    const float* bo    = (const float*)d_in[8];
    const float* gamma = (const float*)d_in[9];
    float* out = (float*)d_out;

    // ws: Qt|Kt|Vt bf16 4MB ea | Opart bf16 x4 16MB | Lpart 256KB | Wb 256KB
    const size_t BNC = (size_t)NBATCH * NPIX * CBOT;   // 2M elems
    unsigned short* Qt    = (unsigned short*)d_ws;
    unsigned short* Kt    = Qt + BNC;
    unsigned short* Vt    = Kt + BNC;
    unsigned short* Opart = Vt + BNC;
    float*          Lpart = (float*)(Opart + (size_t)NPART * BNC);
    unsigned short* Wb    = (unsigned short*)(Lpart + (size_t)NPART * NBATCH * NPIX);

    k_wcvt <<<dim3(128),               256, 0, stream>>>(Wq, Wk, Wv, Wo, Wb);
    k_qkvx <<<dim3(128, NBATCH),       256, 0, stream>>>(X, Wb, bq, bk, bv, Qt, Kt, Vt);
    k_flash<<<dim3(32, NPART, NBATCH), 256, 0, stream>>>(Qt, Kt, Vt, Opart, Lpart);
    k_oproj<<<dim3(128, NBATCH),       256, 0, stream>>>(Opart, Lpart, Wb + 98304, bo, gamma, X, out);
}